// Round 5
// baseline (211.405 us; speedup 1.0000x reference)
//
#include <hip/hip_runtime.h>

// B=64,T=128,D=U=1024. M=8192 independent rows.
//   h' = reset?0:state
//   z = sig(x@wi_z + h'@wh_z + bz); r = sig(x@wi_r + h'@wh_r + br)
//   a = tanh(x@wi_a + (r*h')@wh_a + ba)   // (r*h') @ w  — * binds left of @
//   h_new = (1-z)h' + z*a; out = [h_new, h_new]
// Round 5: quad-buffered BK=32 chunks, 8 waves, per-wave 128x64 (zr) /
// 64x64 (cand), counted vmcnt, setprio MFMA clusters, 64B-row swizzle.
//   zr:   M8192 N2048 K2048 (A=xhc=[x|h']), 256 blocks of 256x256
//   cand: M8192 N1024 K2048 (A=[x|rh]),     256 blocks of 256x128

typedef __attribute__((ext_vector_type(8))) short short8;
typedef __attribute__((ext_vector_type(4))) short short4v;
typedef __attribute__((ext_vector_type(4))) float floatx4;
typedef __attribute__((ext_vector_type(4))) float f32x4;

#define MROWS 8192
#define KTOT 2048
#define NU 1024
#define BK 32
#define NCHUNK 64
#define ZR_CHUNKB 32768
#define ZR_LDS (4 * 32768)
#define CD_CHUNKB 24576
#define CD_LDS (4 * 24576)

__device__ __forceinline__ short f2bf(float f) {
  unsigned u = __builtin_bit_cast(unsigned, f);
  u += 0x7fffu + ((u >> 16) & 1u);  // RNE
  return (short)(u >> 16);
}
__device__ __forceinline__ float bf2f(short s) {
  unsigned u = ((unsigned)(unsigned short)s) << 16;
  return __builtin_bit_cast(float, u);
}
__device__ __forceinline__ float sigmoid_f(float v) { return 1.f / (1.f + __expf(-v)); }
__device__ __forceinline__ float tanh_f(float v) {
  float c = fminf(fmaxf(v, -15.f), 15.f);
  float e = __expf(2.f * c);
  return (e - 1.f) / (e + 1.f);
}

typedef __attribute__((address_space(3))) void* lds_vp;
typedef const __attribute__((address_space(1))) void* gbl_vp;
__device__ __forceinline__ void gload16(const void* g, void* lds) {
  __builtin_amdgcn_global_load_lds((gbl_vp)g, (lds_vp)lds, 16, 0, 0);
}

#define MF(a, b, c) __builtin_amdgcn_mfma_f32_16x16x32_bf16(a, b, c, 0, 0, 0)
#define VMCNT_(n) asm volatile("s_waitcnt vmcnt(" #n ")" ::: "memory")
#define VMCNT(n) VMCNT_(n)
#define TILE_BAR()                  \
  do {                              \
    __builtin_amdgcn_s_barrier();   \
    asm volatile("" ::: "memory");  \
  } while (0)

// ---- prep 1: Wc[n][k] = (k<1024 ? w_i[k][n] : w_h[k-1024][n]) bf16 ----
__global__ __launch_bounds__(256) void wt_kernel(const float* __restrict__ w_i,
                                                 const float* __restrict__ w_h,
                                                 short* __restrict__ Wc) {
  __shared__ float tile[32][33];
  const int kb = blockIdx.x * 32;
  const int nb = blockIdx.y * 32;
  const float* src = (kb < 1024) ? w_i : w_h;
  const int kbl = kb & 1023;
  const int tx = threadIdx.x & 31;
  const int ty = threadIdx.x >> 5;
#pragma unroll
  for (int r = 0; r < 32; r += 8)
    tile[ty + r][tx] = src[(size_t)(kbl + ty + r) * 3072 + nb + tx];
  __syncthreads();
#pragma unroll
  for (int r = 0; r < 32; r += 8)
    Wc[(size_t)(nb + ty + r) * KTOT + kb + tx] = f2bf(tile[tx][ty + r]);
}

// ---- prep 2: xh_cat[m] = [bf16(x[m]) | bf16(reset?0:state[m])] ----
__global__ __launch_bounds__(256) void xh_kernel(const float* __restrict__ x,
                                                 const int* __restrict__ reset,
                                                 const float* __restrict__ state,
                                                 short* __restrict__ xhc) {
  const size_t i4 = (size_t)blockIdx.x * blockDim.x + threadIdx.x;
  const size_t e = i4 * 4;
  const int row = (int)(e >> 10);
  const int d = (int)(e & 1023);
  const float hm = reset[row] ? 0.f : 1.f;
  floatx4 fx = *(const floatx4*)(x + e);
  floatx4 fh = *(const floatx4*)(state + e);
  short4v cx, ch;
#pragma unroll
  for (int k = 0; k < 4; ++k) { cx[k] = f2bf(fx[k]); ch[k] = f2bf(fh[k] * hm); }
  *(short4v*)(xhc + (size_t)row * KTOT + d) = cx;
  *(short4v*)(xhc + (size_t)row * KTOT + 1024 + d) = ch;
}

// ================= zr: 256x256 tile, per-wave 128x64 =================
__global__ __launch_bounds__(512, 2) void zr_kernel(
    const short* __restrict__ xhc, const short* __restrict__ Wc,
    const float* __restrict__ bias, float* __restrict__ zbuf,
    short* __restrict__ rh) {
  extern __shared__ char lds[];
  const int tid = threadIdx.x;
  const int wave = tid >> 6, lane = tid & 63;
  const int wm = wave >> 2, wn = wave & 3;         // 2M x 4N waves
  const int lrow = lane & 15;
  const int rdslot = ((lane >> 4) ^ ((lrow >> 1) & 3)) << 4;  // swizzled 16B slot
  const int aoff = (wm * 128 + lrow) * 64 + rdslot;
  const int boff = 16384 + (wn * 64 + lrow) * 64 + rdslot;
  const int dA0 = wave * 1024, dA1 = dA0 + 8192;
  const int dB0 = 16384 + wave * 1024, dB1 = dB0 + 8192;
  const int sr = lane >> 2;
  const int scol = ((lane & 3) ^ ((lane >> 3) & 3)) * 8;  // pre-swizzled k-col

  const int ntile = blockIdx.x & 7, mtile = blockIdx.x >> 3;  // 8 XCD-aligned N-panels
  const int m0 = mtile * 256, n0g = ntile * 256;

  const short* aS = xhc + (size_t)(m0 + wave * 16 + sr) * KTOT + scol;
  const short* aS2 = aS + (size_t)128 * KTOT;
  const short* bS = Wc + (size_t)(n0g + wave * 16 + sr) * KTOT + scol;
  const short* bS2 = bS + (size_t)128 * KTOT;

  f32x4 acc[8][4];
#pragma unroll
  for (int i = 0; i < 8; ++i)
#pragma unroll
    for (int j = 0; j < 4; ++j) acc[i][j] = (f32x4){0.f, 0.f, 0.f, 0.f};

#define ZR_STAGE(ct, bufp)               \
  gload16(aS + (ct) * BK, (bufp) + dA0); \
  gload16(aS2 + (ct) * BK, (bufp) + dA1);\
  gload16(bS + (ct) * BK, (bufp) + dB0); \
  gload16(bS2 + (ct) * BK, (bufp) + dB1);

  ZR_STAGE(0, lds);
  ZR_STAGE(1, lds + ZR_CHUNKB);
  ZR_STAGE(2, lds + 2 * ZR_CHUNKB);
  VMCNT(8);
  TILE_BAR();

#pragma unroll 4
  for (int c = 0; c < NCHUNK; ++c) {
    const char* bb = lds + (c & 3) * ZR_CHUNKB;
    short8 af[8], bq[4];
#pragma unroll
    for (int i = 0; i < 8; ++i) af[i] = *(const short8*)(bb + aoff + i * 1024);
#pragma unroll
    for (int j = 0; j < 4; ++j) bq[j] = *(const short8*)(bb + boff + j * 1024);
    if (c + 3 < NCHUNK) {
      char* nb = lds + ((c + 3) & 3) * ZR_CHUNKB;
      ZR_STAGE(c + 3, nb);
    }
    TILE_BAR();
    __builtin_amdgcn_s_setprio(1);
#pragma unroll
    for (int i = 0; i < 8; ++i)
#pragma unroll
      for (int j = 0; j < 4; ++j) acc[i][j] = MF(af[i], bq[j], acc[i][j]);
    __builtin_amdgcn_s_setprio(0);
    if (c + 3 < NCHUNK) { VMCNT(8); }
    else if (c + 2 < NCHUNK) { VMCNT(4); }
    else if (c + 1 < NCHUNK) { VMCNT(0); }
    TILE_BAR();
  }
#undef ZR_STAGE

  const bool zh = (n0g < 1024);
#pragma unroll
  for (int j = 0; j < 4; ++j) {
    const int gcn = n0g + wn * 64 + j * 16 + lrow;
    const float bv = bias[gcn];
#pragma unroll
    for (int i = 0; i < 8; ++i) {
#pragma unroll
      for (int rg = 0; rg < 4; ++rg) {
        const int gr = m0 + wm * 128 + i * 16 + (lane >> 4) * 4 + rg;
        const float sv = sigmoid_f(acc[i][j][rg] + bv);
        if (zh) {
          zbuf[(size_t)gr * NU + gcn] = sv;
        } else {
          const int u = gcn - 1024;
          const float hv = bf2f(xhc[(size_t)gr * KTOT + 1024 + u]);
          rh[(size_t)gr * NU + u] = f2bf(sv * hv);
        }
      }
    }
  }
}

// ================= cand: 256x128 tile, per-wave 64x64 =================
__global__ __launch_bounds__(512, 2) void cand_kernel(
    const short* __restrict__ xhc, const short* __restrict__ rh,
    const short* __restrict__ Wc, const float* __restrict__ bias,
    const float* zbuf, float* out) {  // zbuf/out alias d_out: no restrict
  extern __shared__ char lds[];
  const int tid = threadIdx.x;
  const int wave = tid >> 6, lane = tid & 63;
  const int wm = wave >> 1, wn = wave & 1;         // 4M x 2N waves
  const int lrow = lane & 15;
  const int rdslot = ((lane >> 4) ^ ((lrow >> 1) & 3)) << 4;
  const int aoff = (wm * 64 + lrow) * 64 + rdslot;
  const int boff = 16384 + (wn * 64 + lrow) * 64 + rdslot;
  const int dA0 = wave * 1024, dA1 = dA0 + 8192;
  const int dB0 = 16384 + wave * 1024;             // B is 128 rows = 8KB
  const int sr = lane >> 2;
  const int scol = ((lane & 3) ^ ((lane >> 3) & 3)) * 8;

  const int ntile = blockIdx.x & 7, mtile = blockIdx.x >> 3;
  const int m0 = mtile * 256, n0g = ntile * 128;

  const short* aX = xhc + (size_t)(m0 + wave * 16 + sr) * KTOT + scol;   // x part (cols 0..1023)
  const short* aX2 = aX + (size_t)128 * KTOT;
  const short* aR = rh + (size_t)(m0 + wave * 16 + sr) * NU + scol;
  const short* aR2 = aR + (size_t)128 * NU;
  const short* bS = Wc + (size_t)(2048 + n0g + wave * 16 + sr) * KTOT + scol;

  f32x4 acc[4][4];
#pragma unroll
  for (int i = 0; i < 4; ++i)
#pragma unroll
    for (int j = 0; j < 4; ++j) acc[i][j] = (f32x4){0.f, 0.f, 0.f, 0.f};

#define CD_STAGE(ct, bufp)                                      \
  if ((ct) < 32) {                                              \
    gload16(aX + (ct) * BK, (bufp) + dA0);                      \
    gload16(aX2 + (ct) * BK, (bufp) + dA1);                     \
  } else {                                                      \
    gload16(aR + ((ct) - 32) * BK, (bufp) + dA0);               \
    gload16(aR2 + ((ct) - 32) * BK, (bufp) + dA1);              \
  }                                                             \
  gload16(bS + (ct) * BK, (bufp) + dB0);

  CD_STAGE(0, lds);
  CD_STAGE(1, lds + CD_CHUNKB);
  CD_STAGE(2, lds + 2 * CD_CHUNKB);
  VMCNT(6);
  TILE_BAR();

#pragma unroll 4
  for (int c = 0; c < NCHUNK; ++c) {
    const char* bb = lds + (c & 3) * CD_CHUNKB;
    short8 af[4], bq[4];
#pragma unroll
    for (int i = 0; i < 4; ++i) af[i] = *(const short8*)(bb + aoff + i * 1024);
#pragma unroll
    for (int j = 0; j < 4; ++j) bq[j] = *(const short8*)(bb + boff + j * 1024);
    if (c + 3 < NCHUNK) {
      char* nb = lds + ((c + 3) & 3) * CD_CHUNKB;
      CD_STAGE(c + 3, nb);
    }
    TILE_BAR();
    __builtin_amdgcn_s_setprio(1);
#pragma unroll
    for (int i = 0; i < 4; ++i)
#pragma unroll
      for (int j = 0; j < 4; ++j) acc[i][j] = MF(af[i], bq[j], acc[i][j]);
    __builtin_amdgcn_s_setprio(0);
    if (c + 3 < NCHUNK) { VMCNT(6); }
    else if (c + 2 < NCHUNK) { VMCNT(3); }
    else if (c + 1 < NCHUNK) { VMCNT(0); }
    TILE_BAR();
  }
#undef CD_STAGE

#pragma unroll
  for (int j = 0; j < 4; ++j) {
    const int gc = n0g + wn * 64 + j * 16 + lrow;
    const float ba = bias[2048 + gc];
#pragma unroll
    for (int i = 0; i < 4; ++i) {
#pragma unroll
      for (int rg = 0; rg < 4; ++rg) {
        const int gr = m0 + wm * 64 + i * 16 + (lane >> 4) * 4 + rg;
        const float av = tanh_f(acc[i][j][rg] + ba);
        const float zv = zbuf[(size_t)gr * NU + gc];
        const float hv = bf2f(xhc[(size_t)gr * KTOT + 1024 + gc]);
        const float hn = (1.f - zv) * hv + zv * av;
        out[(size_t)gr * NU + gc] = hn;
        out[(size_t)MROWS * NU + (size_t)gr * NU + gc] = hn;  // overwrites zbuf slot (read-first, same thread)
      }
    }
  }
}

extern "C" void kernel_launch(void* const* d_in, const int* in_sizes, int n_in,
                              void* d_out, int out_size, void* d_ws, size_t ws_size,
                              hipStream_t stream) {
  const float* x = (const float*)d_in[0];
  const int* reset = (const int*)d_in[1];
  const float* state = (const float*)d_in[2];
  const float* w_i = (const float*)d_in[3];
  const float* w_h = (const float*)d_in[4];
  const float* bias = (const float*)d_in[5];
  float* out = (float*)d_out;

  short* Wc = (short*)d_ws;                    // [3072][2048] bf16, 12.6MB
  short* xhc = Wc + (size_t)3072 * KTOT;       // [8192][2048] bf16, 33.5MB
  short* rh = xhc + (size_t)MROWS * KTOT;      // [8192][1024] bf16, 16.8MB
  float* zbuf = out + (size_t)MROWS * NU;      // z in d_out 2nd half

  hipFuncSetAttribute(reinterpret_cast<const void*>(zr_kernel),
                      hipFuncAttributeMaxDynamicSharedMemorySize, ZR_LDS);
  hipFuncSetAttribute(reinterpret_cast<const void*>(cand_kernel),
                      hipFuncAttributeMaxDynamicSharedMemorySize, CD_LDS);

  wt_kernel<<<dim3(KTOT / 32, 3072 / 32), 256, 0, stream>>>(w_i, w_h, Wc);
  xh_kernel<<<dim3(MROWS * 1024 / 4 / 256), 256, 0, stream>>>(x, reset, state, xhc);

  zr_kernel<<<dim3(256), 512, ZR_LDS, stream>>>(xhc, Wc, bias, zbuf, rh);
  cand_kernel<<<dim3(256), 512, CD_LDS, stream>>>(xhc, rh, Wc, bias, zbuf, out);
}